// Round 3
// baseline (372.268 us; speedup 1.0000x reference)
//
#include <hip/hip_runtime.h>
#include <math.h>

typedef _Float16 f16;
typedef __attribute__((ext_vector_type(4))) _Float16 f16x4;
typedef __attribute__((ext_vector_type(8))) _Float16 f16x8;
typedef __attribute__((ext_vector_type(4))) float f32x4;

#define B_    4
#define L_    1024
#define H_    768
#define NH_   12
#define NE_   42
#define M_    8
#define E2_   1536              // 2*H
#define HTP_  1792              // HT rows padded to 14*128
#define OUT_HALF 5419008LL      // B*NE*NE*H

// async global->LDS, 16B per lane. LDS dest is wave-uniform base + lane*16B.
typedef __attribute__((address_space(1))) const unsigned char ga_t;
typedef __attribute__((address_space(3))) unsigned char la_t;
__device__ __forceinline__ void async16(const void* g, void* l) {
    __builtin_amdgcn_global_load_lds((ga_t*)g, (la_t*)l, 16, 0, 0);
}

// fast tanh: 1 - 2/(e^{2x}+1) via v_exp_f32. Correct limits at +-inf.
__device__ __forceinline__ float fast_tanh(float x) {
    float e = __expf(2.f * x);
    return 1.f - 2.f / (e + 1.f);
}

// ===================== device bodies =====================

// ---- prep: 32x32 LDS tile transpose W[h][c] -> w*[c][h] (f16) + bias concat
__device__ void prep_body(int bid, char* smem,
                          const float* __restrict__ Wh, const float* __restrict__ Wt,
                          const float* __restrict__ bh, const float* __restrict__ bt,
                          f16* __restrict__ wtop, f16* __restrict__ wbot,
                          float* __restrict__ bcat) {
    float (*tile)[33] = (float(*)[33])smem;           // 32*33*4 = 4224 B
    int tx = bid % 24, ty = (bid / 24) % 24, m = bid / 576;
    const float* src = (m & 1) ? Wt : Wh;
    int roff = (m & 2) ? H_ : 0;
    f16* dst = (m & 2) ? wbot : wtop;
    int coff = (m & 1) ? H_ : 0;
    int x = threadIdx.x & 31, y8 = threadIdx.x >> 5;
#pragma unroll
    for (int r = 0; r < 4; r++) {
        int h = ty*32 + y8 + r*8, c = tx*32 + x;
        tile[y8 + r*8][x] = src[(long long)(roff + h)*H_ + c];
    }
    __syncthreads();
#pragma unroll
    for (int r = 0; r < 4; r++) {
        int c2 = tx*32 + y8 + r*8, h2 = ty*32 + x;
        dst[(long long)(coff + c2)*H_ + h2] = (f16)tile[x][y8 + r*8];
    }
    if (bid == 0) {
        for (int idx = threadIdx.x; idx < E2_; idx += 256)
            bcat[idx] = (idx < H_) ? bh[idx] : bt[idx - H_];
    }
}

// ---- seq f32 -> f16
__device__ void seq16_body(int bid, const float* __restrict__ seq,
                           f16* __restrict__ seq16) {
    int idx = (bid*256 + threadIdx.x) * 4;
    f32x4 v = *(const f32x4*)(seq + idx);
    f16x4 o = {(f16)v[0], (f16)v[1], (f16)v[2], (f16)v[3]};
    *(f16x4*)(seq16 + idx) = o;
}

// ---- ent_emb: masked logsumexp over mentions -> f16 [168][768]
__device__ void ent_emb_body(int bid, const float* __restrict__ seq,
                             const int* __restrict__ mpos,
                             const int* __restrict__ mmask,
                             f16* __restrict__ ent) {
    int e = bid % NE_, b = bid / NE_;
    int tid = threadIdx.x;
    const int* mp = mpos  + (b*NE_ + e)*M_;
    const int* mk = mmask + (b*NE_ + e)*M_;
    int pos[M_], msk[M_];
#pragma unroll
    for (int m = 0; m < M_; m++) { msk[m] = mk[m]; pos[m] = mp[m] + 1; }
#pragma unroll
    for (int q = 0; q < 3; q++) {
        int h = tid + q*256;
        float mx = -1e30f, vals[M_];
#pragma unroll
        for (int m = 0; m < M_; m++) {
            vals[m] = 0.f;
            if (msk[m]) {
                float v = seq[((long long)b*L_ + pos[m])*H_ + h];
                vals[m] = v; mx = fmaxf(mx, v);
            }
        }
        float s = 0.f;
#pragma unroll
        for (int m = 0; m < M_; m++) if (msk[m]) s += __expf(vals[m] - mx);
        float lse = (mx > -1e29f) ? mx + __logf(s) : 0.f;
        ent[(b*NE_ + e)*H_ + h] = (f16)lse;
    }
}

// ---- ent_att: mean over valid mentions -> f16 [B][NE][NH][L]
__device__ void ent_att_body(int bid, const float* __restrict__ attn,
                             const int* __restrict__ mpos,
                             const int* __restrict__ mmask,
                             f16* __restrict__ eatt) {
    int nh = bid % NH_, e = (bid / NH_) % NE_, b = bid / (NH_*NE_);
    int tid = threadIdx.x;
    int l0 = tid * 4;
    const int* mp = mpos  + (b*NE_ + e)*M_;
    const int* mk = mmask + (b*NE_ + e)*M_;
    const float* abase = attn + (long long)(b*NH_ + nh) * L_ * L_;
    f32x4 acc = {0,0,0,0}; int cnt = 0;
#pragma unroll
    for (int m = 0; m < M_; m++) {
        if (mk[m]) {                       // wave-uniform branch
            cnt++;
            const float* row = abase + (long long)(mp[m] + 1) * L_;
            acc += *(const f32x4*)(row + l0);
        }
    }
    float inv = 1.f / (float)(cnt > 0 ? cnt : 1);
    f16x4 o = {(f16)(acc[0]*inv), (f16)(acc[1]*inv), (f16)(acc[2]*inv), (f16)(acc[3]*inv)};
    *(f16x4*)(eatt + ((long long)(b*NE_ + e)*NH_ + nh)*L_ + l0) = o;
}

// ---- ht: (1/NH) sum_h ea_i*ea_j, relu, L-normalize -> f16 HT [B][HTP][L]
__device__ void ht_body(int bid, char* smem, const f16* __restrict__ eatt,
                        f16* __restrict__ HT) {
    int jg = bid % 6, i = (bid / 6) % NE_, b = bid / 252;
    int tid = threadIdx.x;
    f16* ei_s = (f16*)smem;                       // 24576 B
    float (*red)[4] = (float(*)[4])(smem + NH_*L_*2);  // 7*4 floats
    const f16* ei = eatt + (long long)(b*NE_ + i)*NH_*L_;
#pragma unroll
    for (int q = 0; q < 6; q++) {
        int off = (q*256 + tid)*8;
        *(f16x8*)(ei_s + off) = *(const f16x8*)(ei + off);
    }
    __syncthreads();
    int l0 = tid*4;
    int wave = tid >> 6, lane = tid & 63;
    for (int jj = 0; jj < 7; jj++) {
        int j = jg*7 + jj;
        const f16* ej = eatt + (long long)(b*NE_ + j)*NH_*L_;
        f32x4 acc = {0,0,0,0};
#pragma unroll
        for (int h = 0; h < NH_; h++) {
            f16x4 vi = *(const f16x4*)(ei_s + h*L_ + l0);
            f16x4 vj = *(const f16x4*)(ej   + h*L_ + l0);
#pragma unroll
            for (int r = 0; r < 4; r++) acc[r] += (float)vi[r] * (float)vj[r];
        }
        float v[4]; float s = 0.f;
#pragma unroll
        for (int r = 0; r < 4; r++) {
            float t = acc[r] * (1.f/12.f);
            t = t > 0.f ? t : 0.f;
            v[r] = t; s += t;
        }
#pragma unroll
        for (int m = 1; m < 64; m <<= 1) s += __shfl_xor(s, m, 64);
        if (lane == 0) red[jj][wave] = s;
        __syncthreads();                         // single barrier: each jj has own slot
        float S = red[jj][0] + red[jj][1] + red[jj][2] + red[jj][3];
        float sc = 1.f / (S + 1e-10f);
        f16x4 o = {(f16)(v[0]*sc), (f16)(v[1]*sc), (f16)(v[2]*sc), (f16)(v[3]*sc)};
        *(f16x4*)(HT + ((long long)b*HTP_ + i*NE_ + j)*L_ + l0) = o;
    }
}

// ---- small MFMA GEMM 64x64: het = ent @ wtop^T + bcat
#define LDSS 40
__device__ void gemm_het_body(int bx, int by, char* smem,
                              const f16* __restrict__ A, const f16* __restrict__ BT,
                              float* __restrict__ het, const float* __restrict__ bcat) {
    const int M = 168, K = 768;
    f16* As = (f16*)smem;                 // 64*40*2 = 5120 B
    f16* Bs = (f16*)(smem + 64*LDSS*2);   // 5120 B
    int bm = bx*64, bn = by*64;
    int tid = threadIdx.x;
    int wave = tid >> 6, lane = tid & 63;
    int wm = (wave >> 1)*32, wn = (wave & 1)*32;
    int lo4 = lane & 15, kq = (lane >> 4)*8;
    int srow = tid >> 2, scol = (tid & 3)*8;
    bool aval = (bm + srow) < M;
    const f16* aptr = A + (long long)(bm + srow)*K + scol;
    const f16* bptr = BT + (long long)(bn + srow)*K + scol;
    f32x4 acc[2][2] = {};
    for (int k0 = 0; k0 < K; k0 += 32) {
        uint4 zero = {0,0,0,0};
        uint4 av = aval ? *(const uint4*)(aptr + k0) : zero;
        uint4 bv = *(const uint4*)(bptr + k0);
        __syncthreads();
        *(uint4*)(As + srow*LDSS + scol) = av;
        *(uint4*)(Bs + srow*LDSS + scol) = bv;
        __syncthreads();
        f16x8 a0 = *(const f16x8*)(As + (wm +      lo4)*LDSS + kq);
        f16x8 a1 = *(const f16x8*)(As + (wm + 16 + lo4)*LDSS + kq);
        f16x8 b0 = *(const f16x8*)(Bs + (wn +      lo4)*LDSS + kq);
        f16x8 b1 = *(const f16x8*)(Bs + (wn + 16 + lo4)*LDSS + kq);
        acc[0][0] = __builtin_amdgcn_mfma_f32_16x16x32_f16(a0, b0, acc[0][0], 0,0,0);
        acc[0][1] = __builtin_amdgcn_mfma_f32_16x16x32_f16(a0, b1, acc[0][1], 0,0,0);
        acc[1][0] = __builtin_amdgcn_mfma_f32_16x16x32_f16(a1, b0, acc[1][0], 0,0,0);
        acc[1][1] = __builtin_amdgcn_mfma_f32_16x16x32_f16(a1, b1, acc[1][1], 0,0,0);
    }
    int rloc = (lane >> 4)*4;      // C/D: col=lane&15, row=(lane>>4)*4+reg
#pragma unroll
    for (int sm = 0; sm < 2; sm++)
#pragma unroll
    for (int sn = 0; sn < 2; sn++) {
        f32x4 a = acc[sm][sn];
        int c  = bn + wn + sn*16 + lo4;
        int rb = bm + wm + sm*16 + rloc;
#pragma unroll
        for (int r = 0; r < 4; r++)
            if (rb + r < M) het[(rb + r)*E2_ + c] = a[r] + bcat[c];
    }
}

// ---- MFMA f16 GEMM 128x128, BK=32, global_load_lds staging.
// MODE 1: store C transposed f16 -> outp16[bz][c][l]
template<int MODE>
__device__ void gemm2_body(int bx, int by, int bz, char* smem,
                           const f16* __restrict__ A, const f16* __restrict__ BT, int K,
                           long long strideA, long long strideBT,
                           const float* __restrict__ het, float* __restrict__ outp,
                           f16* __restrict__ outp16) {
    f16* As = (f16*)smem;            // 8 KB, unpadded (global_load_lds)
    f16* Bs = (f16*)(smem + 8192);   // 8 KB
    int bm = bx*128, bn = by*128;
    const f16* Ab = A + strideA*bz;
    const f16* Bb = BT + strideBT*bz;
    int tid = threadIdx.x, wave = tid >> 6, lane = tid & 63;
    int wm = (wave >> 1)*64, wn = (wave & 1)*64;
    int lo4 = lane & 15, kq = (lane >> 4)*8;
    int lrow = lane >> 2, lcol = (lane & 3)*8;
    const f16* ag = Ab + (long long)(bm + wave*32 + lrow)*K + lcol;
    const f16* bg = Bb + (long long)(bn + wave*32 + lrow)*K + lcol;
    f16* asl = As + wave*1024;
    f16* bsl = Bs + wave*1024;
    f32x4 acc[4][4] = {};
    for (int k0 = 0; k0 < K; k0 += 32) {
        async16(ag + k0,          asl);
        async16(ag + k0 + 16*K,   asl + 512);
        async16(bg + k0,          bsl);
        async16(bg + k0 + 16*K,   bsl + 512);
        __syncthreads();
        f16x8 af[4], bf[4];
#pragma unroll
        for (int s = 0; s < 4; s++) {
            af[s] = *(const f16x8*)(As + (wm + s*16 + lo4)*32 + kq);
            bf[s] = *(const f16x8*)(Bs + (wn + s*16 + lo4)*32 + kq);
        }
#pragma unroll
        for (int sm = 0; sm < 4; sm++)
#pragma unroll
        for (int sn = 0; sn < 4; sn++)
            acc[sm][sn] = __builtin_amdgcn_mfma_f32_16x16x32_f16(af[sm], bf[sn], acc[sm][sn], 0,0,0);
        __syncthreads();
    }
    int rloc = (lane >> 4)*4;
#pragma unroll
    for (int sm = 0; sm < 4; sm++)
#pragma unroll
    for (int sn = 0; sn < 4; sn++) {
        f32x4 a = acc[sm][sn];
        int c  = bn + wn + sn*16 + lo4;
        int rb = bm + wm + sm*16 + rloc;
        if constexpr (MODE == 1) {
            f16x4 o = {(f16)a[0], (f16)a[1], (f16)a[2], (f16)a[3]};
            *(f16x4*)(outp16 + (long long)bz*E2_*L_ + (long long)c*L_ + rb) = o;
        }
    }
}

// ===================== 256x256 8-phase GEMM for the big output matmul =====================
// A = HT [bz][1792][1024], B^T = seqWT [bz][1536][1024], K=1024, 16 K-tiles of 64.
// 512 threads (8 waves, 2x4), per-wave C = 128x64. LDS 128KB: A,B each 2 buf x 32KB.
// Within region: physical byte = lr*128 + (colbyte ^ ((lr&7)<<4))  [conflict-free b128 reads]
// Staging uses linear LDS dest + inverse-swizzled global source (both-sides-or-neither).
// r3: prefetch lead deepened to >=4 phases for every region (r2 had 2-phase lead < L3
// latency -> per-tile stalls). Stage order per tile t: ph0 B1(t+1), ph1 A1(t+1),
// ph2 A0(t+2), ph3 B0(t+2). Counted waits re-derived (2 loads/stage, worst case):
// steady vmcnt(8) @ph0/ph1/ph3-end, none @ph2; tail t=14.ph3 vmcnt(4), t=15 ph0 vmcnt(2),
// ph1 vmcnt(0).

__device__ __forceinline__ void stage_regionA(const f16* __restrict__ Ab, int bm,
                                              int t, int rq, char* ldsAbuf, int tid) {
    int k0 = t * 64;
    char* wbase = ldsAbuf + rq*16384 + (tid & ~63)*16;
#pragma unroll
    for (int ld = 0; ld < 2; ld++) {
        int o    = (ld*512 + tid) * 16;
        int lr   = o >> 7;
        int colb = o & 127;
        int grow = (lr & 63) + ((lr >> 6) << 7) + rq*64;
        int scolb = colb ^ ((lr & 7) << 4);
        const char* g = (const char*)(Ab + (long long)(bm + grow)*1024 + k0) + scolb;
        async16(g, wbase + ld*8192);
    }
}

__device__ __forceinline__ void stage_regionB(const f16* __restrict__ Bb, int bn,
                                              int t, int cq, char* ldsBbuf, int tid) {
    int k0 = t * 64;
    char* wbase = ldsBbuf + cq*16384 + (tid & ~63)*16;
#pragma unroll
    for (int ld = 0; ld < 2; ld++) {
        int o    = (ld*512 + tid) * 16;
        int lr   = o >> 7;
        int colb = o & 127;
        int brow = ((lr >> 5)*2 + cq)*32 + (lr & 31);
        int scolb = colb ^ ((lr & 7) << 4);
        const char* g = (const char*)(Bb + (long long)(bn + brow)*1024 + k0) + scolb;
        async16(g, wbase + ld*8192);
    }
}

// one phase: ds-read quadrant fragments, issue stage, barrier, MFMA, counted wait, barrier
#define PHASE(RQ, CQ, STAGE_STMT, WAIT_STMT) do {                              \
    f16x8 afr[4][2], bfr[2][2];                                                \
    _Pragma("unroll")                                                          \
    for (int i_ = 0; i_ < 4; i_++) {                                           \
        char* pa_ = bA + (RQ)*16384 + (wr*64 + i_*16 + lo4)*128;               \
        _Pragma("unroll")                                                      \
        for (int ks_ = 0; ks_ < 2; ks_++)                                      \
            afr[i_][ks_] = *(const f16x8*)(pa_ + ((ks_*64 + kq2) ^ sw));       \
    }                                                                          \
    _Pragma("unroll")                                                          \
    for (int j_ = 0; j_ < 2; j_++) {                                           \
        char* pb_ = bB + (CQ)*16384 + (wc*32 + j_*16 + lo4)*128;               \
        _Pragma("unroll")                                                      \
        for (int ks_ = 0; ks_ < 2; ks_++)                                      \
            bfr[j_][ks_] = *(const f16x8*)(pb_ + ((ks_*64 + kq2) ^ sw));       \
    }                                                                          \
    STAGE_STMT;                                                                \
    __builtin_amdgcn_s_barrier();                                              \
    __builtin_amdgcn_sched_barrier(0);                                         \
    asm volatile("" ::: "memory");                                             \
    __builtin_amdgcn_s_setprio(1);                                             \
    _Pragma("unroll")                                                          \
    for (int i_ = 0; i_ < 4; i_++)                                             \
    _Pragma("unroll")                                                          \
    for (int j_ = 0; j_ < 2; j_++) {                                           \
        acc[(RQ)*4+i_][(CQ)*2+j_] = __builtin_amdgcn_mfma_f32_16x16x32_f16(    \
            afr[i_][0], bfr[j_][0], acc[(RQ)*4+i_][(CQ)*2+j_], 0,0,0);         \
        acc[(RQ)*4+i_][(CQ)*2+j_] = __builtin_amdgcn_mfma_f32_16x16x32_f16(    \
            afr[i_][1], bfr[j_][1], acc[(RQ)*4+i_][(CQ)*2+j_], 0,0,0);         \
    }                                                                          \
    __builtin_amdgcn_s_setprio(0);                                             \
    WAIT_STMT;                                                                 \
    __builtin_amdgcn_s_barrier();                                              \
    __builtin_amdgcn_sched_barrier(0);                                         \
    asm volatile("" ::: "memory");                                             \
} while (0)

__global__ __launch_bounds__(512, 2) void k_L3(
        const f16* __restrict__ HT, const f16* __restrict__ seqWT,
        const float* __restrict__ het, float* __restrict__ outp) {
    __shared__ __align__(16) char smem[131072];
    int bm = blockIdx.x*256, bn = blockIdx.y*256, bz = blockIdx.z;
    const f16* Ab = HT + (long long)HTP_*L_*bz;
    const f16* Bb = seqWT + (long long)E2_*L_*bz;
    int tid = threadIdx.x, wave = tid >> 6, lane = tid & 63;
    int wr = wave >> 2, wc = wave & 3;
    int lo4 = lane & 15, kq2 = (lane >> 4)*16;
    int sw = (lo4 & 7) << 4;
    f32x4 acc[8][4] = {};

    // prologue: A0(0),B0(0),B1(0),A1(0),A0(1),B0(1); force A0(0),B0(0)
    stage_regionA(Ab, bm, 0, 0, smem + 0,     tid);
    stage_regionB(Bb, bn, 0, 0, smem + 65536, tid);
    stage_regionB(Bb, bn, 0, 1, smem + 65536, tid);
    stage_regionA(Ab, bm, 0, 1, smem + 0,     tid);
    stage_regionA(Ab, bm, 1, 0, smem + 32768, tid);
    stage_regionB(Bb, bn, 1, 0, smem + 65536 + 32768, tid);
    asm volatile("s_waitcnt vmcnt(8)" ::: "memory");
    __builtin_amdgcn_s_barrier();
    __builtin_amdgcn_sched_barrier(0);
    asm volatile("" ::: "memory");

    for (int t = 0; t < 16; t++) {
        char* bA  = smem + (t & 1)*32768;              // read buffer (parity p)
        char* bB  = smem + 65536 + (t & 1)*32768;
        char* bAn = smem + ((t+1) & 1)*32768;          // next-tile buffer (p^1)
        char* bBn = smem + 65536 + ((t+1) & 1)*32768;
        bool s1 = (t+1 < 16), s2 = (t+2 < 16);

        // ph0: Q(0,0); stage B1(t+1)->bBn (lead 5ph); wait forces B1(t)
        PHASE(0, 0, { if (s1) stage_regionB(Bb, bn, t+1, 1, bBn, tid); },
              { if (t < 15) { asm volatile("s_waitcnt vmcnt(8)" ::: "memory"); }
                else        { asm volatile("s_waitcnt vmcnt(2)" ::: "memory"); } });
        // ph1: Q(0,1); stage A1(t+1)->bAn (lead 5ph); wait forces A1(t)
        PHASE(0, 1, { if (s1) stage_regionA(Ab, bm, t+1, 1, bAn, tid); },
              { if (t < 15) { asm volatile("s_waitcnt vmcnt(8)" ::: "memory"); }
                else        { asm volatile("s_waitcnt vmcnt(0)" ::: "memory"); } });
        // ph2: Q(1,0); stage A0(t+2)->bA, same buffer (readers done at ph1); no wait
        PHASE(1, 0, { if (s2) stage_regionA(Ab, bm, t+2, 0, bA, tid); }, {});
        // ph3: Q(1,1); stage B0(t+2)->bB (readers done at ph2); wait forces A0/B0(t+1)
        PHASE(1, 1, { if (s2) stage_regionB(Bb, bn, t+2, 0, bB, tid); },
              { if (t < 14)       { asm volatile("s_waitcnt vmcnt(8)" ::: "memory"); }
                else if (t == 14) { asm volatile("s_waitcnt vmcnt(4)" ::: "memory"); } });
    }

    // epilogue: bias gather + tanh + split store
    int rloc = (lane >> 4)*4;
#pragma unroll
    for (int sm = 0; sm < 8; sm++)
#pragma unroll
    for (int sn = 0; sn < 4; sn++) {
        f32x4 a = acc[sm][sn];
        int c  = bn + wc*64 + sn*16 + lo4;
        int rb = bm + wr*128 + sm*16 + rloc;
#pragma unroll
        for (int r = 0; r < 4; r++) {
            int row = rb + r;
            if (row < NE_*NE_) {
                int i = row / NE_;
                int j = row - i*NE_;
                int sel = (c < H_) ? i : j;
                float bias = het[(bz*NE_ + sel)*E2_ + c];
                float v = fast_tanh(a[r] + bias);
                long long o = (c < H_)
                    ? ((long long)((bz*NE_ + i)*NE_ + j))*H_ + c
                    : OUT_HALF + ((long long)((bz*NE_ + i)*NE_ + j))*H_ + (c - H_);
                outp[o] = v;
            }
        }
    }
}

// ===================== fused launches =====================
// L1: prep (2304) | seq16 (3072) | ent_emb (168) | ent_att (2016)  = 7560 blocks
__global__ __launch_bounds__(256) void k_L1(
        const float* __restrict__ seq, const float* __restrict__ attn,
        const float* __restrict__ Wh, const float* __restrict__ bh,
        const float* __restrict__ Wt, const float* __restrict__ bt,
        const int* __restrict__ mpos, const int* __restrict__ mmask,
        f16* __restrict__ wtop, f16* __restrict__ wbot, float* __restrict__ bcat,
        f16* __restrict__ seq16, f16* __restrict__ ent, f16* __restrict__ eatt) {
    __shared__ __align__(16) char smem[4224];
    int bid = blockIdx.x;
    if (bid < 2304)       prep_body(bid, smem, Wh, Wt, bh, bt, wtop, wbot, bcat);
    else if (bid < 5376)  seq16_body(bid - 2304, seq, seq16);
    else if (bid < 5544)  ent_emb_body(bid - 5376, seq, mpos, mmask, ent);
    else                  ent_att_body(bid - 5544, attn, mpos, mmask, eatt);
}

// L2: gemm2<1> (384) | ht (1008) | gemm_het (72) = 1464 blocks
__global__ __launch_bounds__(256) void k_L2(
        const f16* __restrict__ seq16, const f16* __restrict__ wbot,
        const f16* __restrict__ ent, const f16* __restrict__ wtop,
        const float* __restrict__ bcat, const f16* __restrict__ eatt,
        f16* __restrict__ seqWT, float* __restrict__ het, f16* __restrict__ HT) {
    __shared__ __align__(16) char smem[24704];
    int bid = blockIdx.x;
    if (bid < 384) {
        int bx = bid & 7, by = (bid >> 3) % 12, bz = bid / 96;
        gemm2_body<1>(bx, by, bz, smem, seq16, wbot, 768,
                      (long long)L_*H_, 0, nullptr, nullptr, seqWT);
    } else if (bid < 1392) {
        ht_body(bid - 384, smem, eatt, HT);
    } else {
        int r = bid - 1392;
        gemm_het_body(r % 3, r / 3, smem, ent, wtop, het, bcat);
    }
}

extern "C" void kernel_launch(void* const* d_in, const int* in_sizes, int n_in,
                              void* d_out, int out_size, void* d_ws, size_t ws_size,
                              hipStream_t stream) {
    const float* seq  = (const float*)d_in[0];
    const float* attn = (const float*)d_in[1];
    const float* Wh   = (const float*)d_in[2];
    const float* bh   = (const float*)d_in[3];
    const float* Wt   = (const float*)d_in[4];
    const float* bt   = (const float*)d_in[5];
    const int* mpos   = (const int*)d_in[6];
    const int* mmask  = (const int*)d_in[7];
    float* out = (float*)d_out;
    char* ws = (char*)d_ws;
    f16*   ent   = (f16*)  (ws + 0);         //  168*768          f16
    f16*   wtop  = (f16*)  (ws + 258048);    // 1536*768          f16 [c][h]
    f16*   wbot  = (f16*)  (ws + 2617344);   // 1536*768          f16 [c][h]
    float* bcat  = (float*)(ws + 4976640);   // 1536              f32
    float* het   = (float*)(ws + 4982784);   //  168*1536         f32
    f16*   eatt  = (f16*)  (ws + 6014976);   // 4*42*12*1024      f16
    f16*   seq16 = (f16*)  (ws + 10143744);  // 4*1024*768        f16
    f16*   HT    = (f16*)  (ws + 16435200);  // 4*1792*1024       f16
    f16*   seqWT = (f16*)  (ws + 31115264);  // 4*1536*1024       f16 (transposed)
    // total 43,698,176 B

    k_L1<<<7560, 256, 0, stream>>>(seq, attn, Wh, bh, Wt, bt, mpos, mmask,
                                   wtop, wbot, bcat, seq16, ent, eatt);
    k_L2<<<1464, 256, 0, stream>>>(seq16, wbot, ent, wtop, bcat, eatt,
                                   seqWT, het, HT);
    k_L3<<<dim3(7, 6, B_), 512, 0, stream>>>(HT, seqWT, het, out);
}

// Round 4
// 368.549 us; speedup vs baseline: 1.0101x; 1.0101x over previous
//
#include <hip/hip_runtime.h>
#include <math.h>

typedef _Float16 f16;
typedef __attribute__((ext_vector_type(4))) _Float16 f16x4;
typedef __attribute__((ext_vector_type(8))) _Float16 f16x8;
typedef __attribute__((ext_vector_type(4))) float f32x4;

#define B_    4
#define L_    1024
#define H_    768
#define NH_   12
#define NE_   42
#define M_    8
#define E2_   1536              // 2*H
#define HTP_  1792              // HT rows padded to 14*128
#define OUT_HALF 5419008LL      // B*NE*NE*H

// async global->LDS, 16B per lane. LDS dest is wave-uniform base + lane*16B.
typedef __attribute__((address_space(1))) const unsigned char ga_t;
typedef __attribute__((address_space(3))) unsigned char la_t;
__device__ __forceinline__ void async16(const void* g, void* l) {
    __builtin_amdgcn_global_load_lds((ga_t*)g, (la_t*)l, 16, 0, 0);
}

// fast tanh: 1 - 2/(e^{2x}+1) via v_exp_f32. Correct limits at +-inf.
__device__ __forceinline__ float fast_tanh(float x) {
    float e = __expf(2.f * x);
    return 1.f - 2.f / (e + 1.f);
}

// ===================== device bodies =====================

// ---- prep: 32x32 LDS tile transpose W[h][c] -> w*[c][h] (f16) + bias concat
__device__ void prep_body(int bid, char* smem,
                          const float* __restrict__ Wh, const float* __restrict__ Wt,
                          const float* __restrict__ bh, const float* __restrict__ bt,
                          f16* __restrict__ wtop, f16* __restrict__ wbot,
                          float* __restrict__ bcat) {
    float (*tile)[33] = (float(*)[33])smem;           // 32*33*4 = 4224 B
    int tx = bid % 24, ty = (bid / 24) % 24, m = bid / 576;
    const float* src = (m & 1) ? Wt : Wh;
    int roff = (m & 2) ? H_ : 0;
    f16* dst = (m & 2) ? wbot : wtop;
    int coff = (m & 1) ? H_ : 0;
    int x = threadIdx.x & 31, y8 = threadIdx.x >> 5;
#pragma unroll
    for (int r = 0; r < 4; r++) {
        int h = ty*32 + y8 + r*8, c = tx*32 + x;
        tile[y8 + r*8][x] = src[(long long)(roff + h)*H_ + c];
    }
    __syncthreads();
#pragma unroll
    for (int r = 0; r < 4; r++) {
        int c2 = tx*32 + y8 + r*8, h2 = ty*32 + x;
        dst[(long long)(coff + c2)*H_ + h2] = (f16)tile[x][y8 + r*8];
    }
    if (bid == 0) {
        for (int idx = threadIdx.x; idx < E2_; idx += 256)
            bcat[idx] = (idx < H_) ? bh[idx] : bt[idx - H_];
    }
}

// ---- seq f32 -> f16
__device__ void seq16_body(int bid, const float* __restrict__ seq,
                           f16* __restrict__ seq16) {
    int idx = (bid*256 + threadIdx.x) * 4;
    f32x4 v = *(const f32x4*)(seq + idx);
    f16x4 o = {(f16)v[0], (f16)v[1], (f16)v[2], (f16)v[3]};
    *(f16x4*)(seq16 + idx) = o;
}

// ---- ent_emb: masked logsumexp over mentions -> f16 [168][768]
__device__ void ent_emb_body(int bid, const float* __restrict__ seq,
                             const int* __restrict__ mpos,
                             const int* __restrict__ mmask,
                             f16* __restrict__ ent) {
    int e = bid % NE_, b = bid / NE_;
    int tid = threadIdx.x;
    const int* mp = mpos  + (b*NE_ + e)*M_;
    const int* mk = mmask + (b*NE_ + e)*M_;
    int pos[M_], msk[M_];
#pragma unroll
    for (int m = 0; m < M_; m++) { msk[m] = mk[m]; pos[m] = mp[m] + 1; }
#pragma unroll
    for (int q = 0; q < 3; q++) {
        int h = tid + q*256;
        float mx = -1e30f, vals[M_];
#pragma unroll
        for (int m = 0; m < M_; m++) {
            vals[m] = 0.f;
            if (msk[m]) {
                float v = seq[((long long)b*L_ + pos[m])*H_ + h];
                vals[m] = v; mx = fmaxf(mx, v);
            }
        }
        float s = 0.f;
#pragma unroll
        for (int m = 0; m < M_; m++) if (msk[m]) s += __expf(vals[m] - mx);
        float lse = (mx > -1e29f) ? mx + __logf(s) : 0.f;
        ent[(b*NE_ + e)*H_ + h] = (f16)lse;
    }
}

// ---- ent_att: mean over valid mentions -> f16 [B][NE][NH][L]
__device__ void ent_att_body(int bid, const float* __restrict__ attn,
                             const int* __restrict__ mpos,
                             const int* __restrict__ mmask,
                             f16* __restrict__ eatt) {
    int nh = bid % NH_, e = (bid / NH_) % NE_, b = bid / (NH_*NE_);
    int tid = threadIdx.x;
    int l0 = tid * 4;
    const int* mp = mpos  + (b*NE_ + e)*M_;
    const int* mk = mmask + (b*NE_ + e)*M_;
    const float* abase = attn + (long long)(b*NH_ + nh) * L_ * L_;
    f32x4 acc = {0,0,0,0}; int cnt = 0;
#pragma unroll
    for (int m = 0; m < M_; m++) {
        if (mk[m]) {                       // wave-uniform branch
            cnt++;
            const float* row = abase + (long long)(mp[m] + 1) * L_;
            acc += *(const f32x4*)(row + l0);
        }
    }
    float inv = 1.f / (float)(cnt > 0 ? cnt : 1);
    f16x4 o = {(f16)(acc[0]*inv), (f16)(acc[1]*inv), (f16)(acc[2]*inv), (f16)(acc[3]*inv)};
    *(f16x4*)(eatt + ((long long)(b*NE_ + e)*NH_ + nh)*L_ + l0) = o;
}

// ---- ht: (1/NH) sum_h ea_i*ea_j, relu, L-normalize -> f16 HT [B][HTP][L]
__device__ void ht_body(int bid, char* smem, const f16* __restrict__ eatt,
                        f16* __restrict__ HT) {
    int jg = bid % 6, i = (bid / 6) % NE_, b = bid / 252;
    int tid = threadIdx.x;
    f16* ei_s = (f16*)smem;                       // 24576 B
    float (*red)[4] = (float(*)[4])(smem + NH_*L_*2);  // 7*4 floats
    const f16* ei = eatt + (long long)(b*NE_ + i)*NH_*L_;
#pragma unroll
    for (int q = 0; q < 6; q++) {
        int off = (q*256 + tid)*8;
        *(f16x8*)(ei_s + off) = *(const f16x8*)(ei + off);
    }
    __syncthreads();
    int l0 = tid*4;
    int wave = tid >> 6, lane = tid & 63;
    for (int jj = 0; jj < 7; jj++) {
        int j = jg*7 + jj;
        const f16* ej = eatt + (long long)(b*NE_ + j)*NH_*L_;
        f32x4 acc = {0,0,0,0};
#pragma unroll
        for (int h = 0; h < NH_; h++) {
            f16x4 vi = *(const f16x4*)(ei_s + h*L_ + l0);
            f16x4 vj = *(const f16x4*)(ej   + h*L_ + l0);
#pragma unroll
            for (int r = 0; r < 4; r++) acc[r] += (float)vi[r] * (float)vj[r];
        }
        float v[4]; float s = 0.f;
#pragma unroll
        for (int r = 0; r < 4; r++) {
            float t = acc[r] * (1.f/12.f);
            t = t > 0.f ? t : 0.f;
            v[r] = t; s += t;
        }
#pragma unroll
        for (int m = 1; m < 64; m <<= 1) s += __shfl_xor(s, m, 64);
        if (lane == 0) red[jj][wave] = s;
        __syncthreads();                         // single barrier: each jj has own slot
        float S = red[jj][0] + red[jj][1] + red[jj][2] + red[jj][3];
        float sc = 1.f / (S + 1e-10f);
        f16x4 o = {(f16)(v[0]*sc), (f16)(v[1]*sc), (f16)(v[2]*sc), (f16)(v[3]*sc)};
        *(f16x4*)(HT + ((long long)b*HTP_ + i*NE_ + j)*L_ + l0) = o;
    }
}

// ---- small MFMA GEMM 64x64: het = ent @ wtop^T + bcat
#define LDSS 40
__device__ void gemm_het_body(int bx, int by, char* smem,
                              const f16* __restrict__ A, const f16* __restrict__ BT,
                              float* __restrict__ het, const float* __restrict__ bcat) {
    const int M = 168, K = 768;
    f16* As = (f16*)smem;                 // 64*40*2 = 5120 B
    f16* Bs = (f16*)(smem + 64*LDSS*2);   // 5120 B
    int bm = bx*64, bn = by*64;
    int tid = threadIdx.x;
    int wave = tid >> 6, lane = tid & 63;
    int wm = (wave >> 1)*32, wn = (wave & 1)*32;
    int lo4 = lane & 15, kq = (lane >> 4)*8;
    int srow = tid >> 2, scol = (tid & 3)*8;
    bool aval = (bm + srow) < M;
    const f16* aptr = A + (long long)(bm + srow)*K + scol;
    const f16* bptr = BT + (long long)(bn + srow)*K + scol;
    f32x4 acc[2][2] = {};
    for (int k0 = 0; k0 < K; k0 += 32) {
        uint4 zero = {0,0,0,0};
        uint4 av = aval ? *(const uint4*)(aptr + k0) : zero;
        uint4 bv = *(const uint4*)(bptr + k0);
        __syncthreads();
        *(uint4*)(As + srow*LDSS + scol) = av;
        *(uint4*)(Bs + srow*LDSS + scol) = bv;
        __syncthreads();
        f16x8 a0 = *(const f16x8*)(As + (wm +      lo4)*LDSS + kq);
        f16x8 a1 = *(const f16x8*)(As + (wm + 16 + lo4)*LDSS + kq);
        f16x8 b0 = *(const f16x8*)(Bs + (wn +      lo4)*LDSS + kq);
        f16x8 b1 = *(const f16x8*)(Bs + (wn + 16 + lo4)*LDSS + kq);
        acc[0][0] = __builtin_amdgcn_mfma_f32_16x16x32_f16(a0, b0, acc[0][0], 0,0,0);
        acc[0][1] = __builtin_amdgcn_mfma_f32_16x16x32_f16(a0, b1, acc[0][1], 0,0,0);
        acc[1][0] = __builtin_amdgcn_mfma_f32_16x16x32_f16(a1, b0, acc[1][0], 0,0,0);
        acc[1][1] = __builtin_amdgcn_mfma_f32_16x16x32_f16(a1, b1, acc[1][1], 0,0,0);
    }
    int rloc = (lane >> 4)*4;      // C/D: col=lane&15, row=(lane>>4)*4+reg
#pragma unroll
    for (int sm = 0; sm < 2; sm++)
#pragma unroll
    for (int sn = 0; sn < 2; sn++) {
        f32x4 a = acc[sm][sn];
        int c  = bn + wn + sn*16 + lo4;
        int rb = bm + wm + sm*16 + rloc;
#pragma unroll
        for (int r = 0; r < 4; r++)
            if (rb + r < M) het[(rb + r)*E2_ + c] = a[r] + bcat[c];
    }
}

// ---- MFMA f16 GEMM 128x128, BK=32, global_load_lds staging.
// MODE 1: store C transposed f16 -> outp16[bz][c][l]
template<int MODE>
__device__ void gemm2_body(int bx, int by, int bz, char* smem,
                           const f16* __restrict__ A, const f16* __restrict__ BT, int K,
                           long long strideA, long long strideBT,
                           const float* __restrict__ het, float* __restrict__ outp,
                           f16* __restrict__ outp16) {
    f16* As = (f16*)smem;            // 8 KB, unpadded (global_load_lds)
    f16* Bs = (f16*)(smem + 8192);   // 8 KB
    int bm = bx*128, bn = by*128;
    const f16* Ab = A + strideA*bz;
    const f16* Bb = BT + strideBT*bz;
    int tid = threadIdx.x, wave = tid >> 6, lane = tid & 63;
    int wm = (wave >> 1)*64, wn = (wave & 1)*64;
    int lo4 = lane & 15, kq = (lane >> 4)*8;
    int lrow = lane >> 2, lcol = (lane & 3)*8;
    const f16* ag = Ab + (long long)(bm + wave*32 + lrow)*K + lcol;
    const f16* bg = Bb + (long long)(bn + wave*32 + lrow)*K + lcol;
    f16* asl = As + wave*1024;
    f16* bsl = Bs + wave*1024;
    f32x4 acc[4][4] = {};
    for (int k0 = 0; k0 < K; k0 += 32) {
        async16(ag + k0,          asl);
        async16(ag + k0 + 16*K,   asl + 512);
        async16(bg + k0,          bsl);
        async16(bg + k0 + 16*K,   bsl + 512);
        __syncthreads();
        f16x8 af[4], bf[4];
#pragma unroll
        for (int s = 0; s < 4; s++) {
            af[s] = *(const f16x8*)(As + (wm + s*16 + lo4)*32 + kq);
            bf[s] = *(const f16x8*)(Bs + (wn + s*16 + lo4)*32 + kq);
        }
#pragma unroll
        for (int sm = 0; sm < 4; sm++)
#pragma unroll
        for (int sn = 0; sn < 4; sn++)
            acc[sm][sn] = __builtin_amdgcn_mfma_f32_16x16x32_f16(af[sm], bf[sn], acc[sm][sn], 0,0,0);
        __syncthreads();
    }
    int rloc = (lane >> 4)*4;
#pragma unroll
    for (int sm = 0; sm < 4; sm++)
#pragma unroll
    for (int sn = 0; sn < 4; sn++) {
        f32x4 a = acc[sm][sn];
        int c  = bn + wn + sn*16 + lo4;
        int rb = bm + wm + sm*16 + rloc;
        if constexpr (MODE == 1) {
            f16x4 o = {(f16)a[0], (f16)a[1], (f16)a[2], (f16)a[3]};
            *(f16x4*)(outp16 + (long long)bz*E2_*L_ + (long long)c*L_ + rb) = o;
        }
    }
}

// ===================== 256x256 8-phase GEMM for the big output matmul =====================
// A = HT [bz][1792][1024], B^T = seqWT [bz][1536][1024], K=1024, 16 K-tiles of 64.
// 512 threads (8 waves, 2x4), per-wave C = 128x64. LDS 128KB: A,B each 2 buf x 32KB.
// Within region: physical byte = lr*128 + (colbyte ^ ((lr&7)<<4))  [conflict-free b128 reads]
// Staging uses linear LDS dest + inverse-swizzled global source (both-sides-or-neither).
// r4: r3 counters showed fetch-bound (FETCH 88MB vs 26MB unique, 1.07 TB/s, MfmaUtil 7%,
// bank-conflict 0) -> add bijective XCD swizzle (T1): 168 blocks = 8 XCDs x 21, ordered so
// one XCD's 21 consecutive lids share A-panels (6-block bx-groups) and reuse B-panels 3-4x.

__device__ __forceinline__ void stage_regionA(const f16* __restrict__ Ab, int bm,
                                              int t, int rq, char* ldsAbuf, int tid) {
    int k0 = t * 64;
    char* wbase = ldsAbuf + rq*16384 + (tid & ~63)*16;
#pragma unroll
    for (int ld = 0; ld < 2; ld++) {
        int o    = (ld*512 + tid) * 16;
        int lr   = o >> 7;
        int colb = o & 127;
        int grow = (lr & 63) + ((lr >> 6) << 7) + rq*64;
        int scolb = colb ^ ((lr & 7) << 4);
        const char* g = (const char*)(Ab + (long long)(bm + grow)*1024 + k0) + scolb;
        async16(g, wbase + ld*8192);
    }
}

__device__ __forceinline__ void stage_regionB(const f16* __restrict__ Bb, int bn,
                                              int t, int cq, char* ldsBbuf, int tid) {
    int k0 = t * 64;
    char* wbase = ldsBbuf + cq*16384 + (tid & ~63)*16;
#pragma unroll
    for (int ld = 0; ld < 2; ld++) {
        int o    = (ld*512 + tid) * 16;
        int lr   = o >> 7;
        int colb = o & 127;
        int brow = ((lr >> 5)*2 + cq)*32 + (lr & 31);
        int scolb = colb ^ ((lr & 7) << 4);
        const char* g = (const char*)(Bb + (long long)(bn + brow)*1024 + k0) + scolb;
        async16(g, wbase + ld*8192);
    }
}

// one phase: ds-read quadrant fragments, issue stage, barrier, MFMA, counted wait, barrier
#define PHASE(RQ, CQ, STAGE_STMT, WAIT_STMT) do {                              \
    f16x8 afr[4][2], bfr[2][2];                                                \
    _Pragma("unroll")                                                          \
    for (int i_ = 0; i_ < 4; i_++) {                                           \
        char* pa_ = bA + (RQ)*16384 + (wr*64 + i_*16 + lo4)*128;               \
        _Pragma("unroll")                                                      \
        for (int ks_ = 0; ks_ < 2; ks_++)                                      \
            afr[i_][ks_] = *(const f16x8*)(pa_ + ((ks_*64 + kq2) ^ sw));       \
    }                                                                          \
    _Pragma("unroll")                                                          \
    for (int j_ = 0; j_ < 2; j_++) {                                           \
        char* pb_ = bB + (CQ)*16384 + (wc*32 + j_*16 + lo4)*128;               \
        _Pragma("unroll")                                                      \
        for (int ks_ = 0; ks_ < 2; ks_++)                                      \
            bfr[j_][ks_] = *(const f16x8*)(pb_ + ((ks_*64 + kq2) ^ sw));       \
    }                                                                          \
    STAGE_STMT;                                                                \
    __builtin_amdgcn_s_barrier();                                              \
    __builtin_amdgcn_sched_barrier(0);                                         \
    asm volatile("" ::: "memory");                                             \
    __builtin_amdgcn_s_setprio(1);                                             \
    _Pragma("unroll")                                                          \
    for (int i_ = 0; i_ < 4; i_++)                                             \
    _Pragma("unroll")                                                          \
    for (int j_ = 0; j_ < 2; j_++) {                                           \
        acc[(RQ)*4+i_][(CQ)*2+j_] = __builtin_amdgcn_mfma_f32_16x16x32_f16(    \
            afr[i_][0], bfr[j_][0], acc[(RQ)*4+i_][(CQ)*2+j_], 0,0,0);         \
        acc[(RQ)*4+i_][(CQ)*2+j_] = __builtin_amdgcn_mfma_f32_16x16x32_f16(    \
            afr[i_][1], bfr[j_][1], acc[(RQ)*4+i_][(CQ)*2+j_], 0,0,0);         \
    }                                                                          \
    __builtin_amdgcn_s_setprio(0);                                             \
    WAIT_STMT;                                                                 \
    __builtin_amdgcn_s_barrier();                                              \
    __builtin_amdgcn_sched_barrier(0);                                         \
    asm volatile("" ::: "memory");                                             \
} while (0)

__global__ __launch_bounds__(512, 2) void k_L3(
        const f16* __restrict__ HT, const f16* __restrict__ seqWT,
        const float* __restrict__ het, float* __restrict__ outp) {
    __shared__ __align__(16) char smem[131072];
    // Bijective XCD swizzle: nwg = 168 = 8 * 21. Consecutive lids on one XCD share
    // A-panels (lid = bz*42 + bx*6 + by: 6-block runs share (bz,bx); by cycles reuse B).
    int orig = blockIdx.x;
    int lid  = (orig & 7) * 21 + (orig >> 3);
    int bz   = lid / 42;
    int rem  = lid - bz*42;
    int bx   = rem / 6;
    int by   = rem - bx*6;
    int bm = bx*256, bn = by*256;
    const f16* Ab = HT + (long long)HTP_*L_*bz;
    const f16* Bb = seqWT + (long long)E2_*L_*bz;
    int tid = threadIdx.x, wave = tid >> 6, lane = tid & 63;
    int wr = wave >> 2, wc = wave & 3;
    int lo4 = lane & 15, kq2 = (lane >> 4)*16;
    int sw = (lo4 & 7) << 4;
    f32x4 acc[8][4] = {};

    // prologue: A0(0),B0(0),B1(0),A1(0),A0(1),B0(1); force A0(0),B0(0)
    stage_regionA(Ab, bm, 0, 0, smem + 0,     tid);
    stage_regionB(Bb, bn, 0, 0, smem + 65536, tid);
    stage_regionB(Bb, bn, 0, 1, smem + 65536, tid);
    stage_regionA(Ab, bm, 0, 1, smem + 0,     tid);
    stage_regionA(Ab, bm, 1, 0, smem + 32768, tid);
    stage_regionB(Bb, bn, 1, 0, smem + 65536 + 32768, tid);
    asm volatile("s_waitcnt vmcnt(8)" ::: "memory");
    __builtin_amdgcn_s_barrier();
    __builtin_amdgcn_sched_barrier(0);
    asm volatile("" ::: "memory");

    for (int t = 0; t < 16; t++) {
        char* bA  = smem + (t & 1)*32768;              // read buffer (parity p)
        char* bB  = smem + 65536 + (t & 1)*32768;
        char* bAn = smem + ((t+1) & 1)*32768;          // next-tile buffer (p^1)
        char* bBn = smem + 65536 + ((t+1) & 1)*32768;
        bool s1 = (t+1 < 16), s2 = (t+2 < 16);

        // ph0: Q(0,0); stage B1(t+1)->bBn (lead 5ph); wait forces B1(t)
        PHASE(0, 0, { if (s1) stage_regionB(Bb, bn, t+1, 1, bBn, tid); },
              { if (t < 15) { asm volatile("s_waitcnt vmcnt(8)" ::: "memory"); }
                else        { asm volatile("s_waitcnt vmcnt(2)" ::: "memory"); } });
        // ph1: Q(0,1); stage A1(t+1)->bAn (lead 5ph); wait forces A1(t)
        PHASE(0, 1, { if (s1) stage_regionA(Ab, bm, t+1, 1, bAn, tid); },
              { if (t < 15) { asm volatile("s_waitcnt vmcnt(8)" ::: "memory"); }
                else        { asm volatile("s_waitcnt vmcnt(0)" ::: "memory"); } });
        // ph2: Q(1,0); stage A0(t+2)->bA, same buffer (readers done at ph1); no wait
        PHASE(1, 0, { if (s2) stage_regionA(Ab, bm, t+2, 0, bA, tid); }, {});
        // ph3: Q(1,1); stage B0(t+2)->bB (readers done at ph2); wait forces A0/B0(t+1)
        PHASE(1, 1, { if (s2) stage_regionB(Bb, bn, t+2, 0, bB, tid); },
              { if (t < 14)       { asm volatile("s_waitcnt vmcnt(8)" ::: "memory"); }
                else if (t == 14) { asm volatile("s_waitcnt vmcnt(4)" ::: "memory"); } });
    }

    // epilogue: bias gather + tanh + split store
    int rloc = (lane >> 4)*4;
#pragma unroll
    for (int sm = 0; sm < 8; sm++)
#pragma unroll
    for (int sn = 0; sn < 4; sn++) {
        f32x4 a = acc[sm][sn];
        int c  = bn + wc*64 + sn*16 + lo4;
        int rb = bm + wr*128 + sm*16 + rloc;
#pragma unroll
        for (int r = 0; r < 4; r++) {
            int row = rb + r;
            if (row < NE_*NE_) {
                int i = row / NE_;
                int j = row - i*NE_;
                int sel = (c < H_) ? i : j;
                float bias = het[(bz*NE_ + sel)*E2_ + c];
                float v = fast_tanh(a[r] + bias);
                long long o = (c < H_)
                    ? ((long long)((bz*NE_ + i)*NE_ + j))*H_ + c
                    : OUT_HALF + ((long long)((bz*NE_ + i)*NE_ + j))*H_ + (c - H_);
                outp[o] = v;
            }
        }
    }
}

// ===================== fused launches =====================
// L1: prep (2304) | seq16 (3072) | ent_emb (168) | ent_att (2016)  = 7560 blocks
__global__ __launch_bounds__(256) void k_L1(
        const float* __restrict__ seq, const float* __restrict__ attn,
        const float* __restrict__ Wh, const float* __restrict__ bh,
        const float* __restrict__ Wt, const float* __restrict__ bt,
        const int* __restrict__ mpos, const int* __restrict__ mmask,
        f16* __restrict__ wtop, f16* __restrict__ wbot, float* __restrict__ bcat,
        f16* __restrict__ seq16, f16* __restrict__ ent, f16* __restrict__ eatt) {
    __shared__ __align__(16) char smem[4224];
    int bid = blockIdx.x;
    if (bid < 2304)       prep_body(bid, smem, Wh, Wt, bh, bt, wtop, wbot, bcat);
    else if (bid < 5376)  seq16_body(bid - 2304, seq, seq16);
    else if (bid < 5544)  ent_emb_body(bid - 5376, seq, mpos, mmask, ent);
    else                  ent_att_body(bid - 5544, attn, mpos, mmask, eatt);
}

// L2: gemm2<1> (384) | ht (1008) | gemm_het (72) = 1464 blocks
__global__ __launch_bounds__(256) void k_L2(
        const f16* __restrict__ seq16, const f16* __restrict__ wbot,
        const f16* __restrict__ ent, const f16* __restrict__ wtop,
        const float* __restrict__ bcat, const f16* __restrict__ eatt,
        f16* __restrict__ seqWT, float* __restrict__ het, f16* __restrict__ HT) {
    __shared__ __align__(16) char smem[24704];
    int bid = blockIdx.x;
    if (bid < 384) {
        int bx = bid & 7, by = (bid >> 3) % 12, bz = bid / 96;
        gemm2_body<1>(bx, by, bz, smem, seq16, wbot, 768,
                      (long long)L_*H_, 0, nullptr, nullptr, seqWT);
    } else if (bid < 1392) {
        ht_body(bid - 384, smem, eatt, HT);
    } else {
        int r = bid - 1392;
        gemm_het_body(r % 3, r / 3, smem, ent, wtop, het, bcat);
    }
}

extern "C" void kernel_launch(void* const* d_in, const int* in_sizes, int n_in,
                              void* d_out, int out_size, void* d_ws, size_t ws_size,
                              hipStream_t stream) {
    const float* seq  = (const float*)d_in[0];
    const float* attn = (const float*)d_in[1];
    const float* Wh   = (const float*)d_in[2];
    const float* bh   = (const float*)d_in[3];
    const float* Wt   = (const float*)d_in[4];
    const float* bt   = (const float*)d_in[5];
    const int* mpos   = (const int*)d_in[6];
    const int* mmask  = (const int*)d_in[7];
    float* out = (float*)d_out;
    char* ws = (char*)d_ws;
    f16*   ent   = (f16*)  (ws + 0);         //  168*768          f16
    f16*   wtop  = (f16*)  (ws + 258048);    // 1536*768          f16 [c][h]
    f16*   wbot  = (f16*)  (ws + 2617344);   // 1536*768          f16 [c][h]
    float* bcat  = (float*)(ws + 4976640);   // 1536              f32
    float* het   = (float*)(ws + 4982784);   //  168*1536         f32
    f16*   eatt  = (f16*)  (ws + 6014976);   // 4*42*12*1024      f16
    f16*   seq16 = (f16*)  (ws + 10143744);  // 4*1024*768        f16
    f16*   HT    = (f16*)  (ws + 16435200);  // 4*1792*1024       f16
    f16*   seqWT = (f16*)  (ws + 31115264);  // 4*1536*1024       f16 (transposed)
    // total 43,698,176 B

    k_L1<<<7560, 256, 0, stream>>>(seq, attn, Wh, bh, Wt, bt, mpos, mmask,
                                   wtop, wbot, bcat, seq16, ent, eatt);
    k_L2<<<1464, 256, 0, stream>>>(seq16, wbot, ent, wtop, bcat, eatt,
                                   seqWT, het, HT);
    k_L3<<<168, 512, 0, stream>>>(HT, seqWT, het, out);
}

// Round 5
// 353.111 us; speedup vs baseline: 1.0543x; 1.0437x over previous
//
#include <hip/hip_runtime.h>
#include <math.h>

typedef _Float16 f16;
typedef __attribute__((ext_vector_type(4))) _Float16 f16x4;
typedef __attribute__((ext_vector_type(8))) _Float16 f16x8;
typedef __attribute__((ext_vector_type(4))) float f32x4;

#define B_    4
#define L_    1024
#define H_    768
#define NH_   12
#define NE_   42
#define M_    8
#define E2_   1536              // 2*H
#define HTP_  1792              // HT rows padded to 14*128
#define OUT_HALF 5419008LL      // B*NE*NE*H

// async global->LDS, 16B per lane. LDS dest is wave-uniform base + lane*16B.
typedef __attribute__((address_space(1))) const unsigned char ga_t;
typedef __attribute__((address_space(3))) unsigned char la_t;
__device__ __forceinline__ void async16(const void* g, void* l) {
    __builtin_amdgcn_global_load_lds((ga_t*)g, (la_t*)l, 16, 0, 0);
}

// fast tanh: 1 - 2/(e^{2x}+1) via v_exp_f32. Correct limits at +-inf.
__device__ __forceinline__ float fast_tanh(float x) {
    float e = __expf(2.f * x);
    return 1.f - 2.f / (e + 1.f);
}

// ===================== device bodies =====================

// ---- prep: 32x32 LDS tile transpose W[h][c] -> w*[c][h] (f16) + bias concat
__device__ void prep_body(int bid, char* smem,
                          const float* __restrict__ Wh, const float* __restrict__ Wt,
                          const float* __restrict__ bh, const float* __restrict__ bt,
                          f16* __restrict__ wtop, f16* __restrict__ wbot,
                          float* __restrict__ bcat) {
    float (*tile)[33] = (float(*)[33])smem;           // 32*33*4 = 4224 B
    int tx = bid % 24, ty = (bid / 24) % 24, m = bid / 576;
    const float* src = (m & 1) ? Wt : Wh;
    int roff = (m & 2) ? H_ : 0;
    f16* dst = (m & 2) ? wbot : wtop;
    int coff = (m & 1) ? H_ : 0;
    int x = threadIdx.x & 31, y8 = threadIdx.x >> 5;
#pragma unroll
    for (int r = 0; r < 4; r++) {
        int h = ty*32 + y8 + r*8, c = tx*32 + x;
        tile[y8 + r*8][x] = src[(long long)(roff + h)*H_ + c];
    }
    __syncthreads();
#pragma unroll
    for (int r = 0; r < 4; r++) {
        int c2 = tx*32 + y8 + r*8, h2 = ty*32 + x;
        dst[(long long)(coff + c2)*H_ + h2] = (f16)tile[x][y8 + r*8];
    }
    if (bid == 0) {
        for (int idx = threadIdx.x; idx < E2_; idx += 256)
            bcat[idx] = (idx < H_) ? bh[idx] : bt[idx - H_];
    }
}

// ---- seq f32 -> f16
__device__ void seq16_body(int bid, const float* __restrict__ seq,
                           f16* __restrict__ seq16) {
    int idx = (bid*256 + threadIdx.x) * 4;
    f32x4 v = *(const f32x4*)(seq + idx);
    f16x4 o = {(f16)v[0], (f16)v[1], (f16)v[2], (f16)v[3]};
    *(f16x4*)(seq16 + idx) = o;
}

// ---- ent_emb: masked logsumexp over mentions -> f16 [168][768]
__device__ void ent_emb_body(int bid, const float* __restrict__ seq,
                             const int* __restrict__ mpos,
                             const int* __restrict__ mmask,
                             f16* __restrict__ ent) {
    int e = bid % NE_, b = bid / NE_;
    int tid = threadIdx.x;
    const int* mp = mpos  + (b*NE_ + e)*M_;
    const int* mk = mmask + (b*NE_ + e)*M_;
    int pos[M_], msk[M_];
#pragma unroll
    for (int m = 0; m < M_; m++) { msk[m] = mk[m]; pos[m] = mp[m] + 1; }
#pragma unroll
    for (int q = 0; q < 3; q++) {
        int h = tid + q*256;
        float mx = -1e30f, vals[M_];
#pragma unroll
        for (int m = 0; m < M_; m++) {
            vals[m] = 0.f;
            if (msk[m]) {
                float v = seq[((long long)b*L_ + pos[m])*H_ + h];
                vals[m] = v; mx = fmaxf(mx, v);
            }
        }
        float s = 0.f;
#pragma unroll
        for (int m = 0; m < M_; m++) if (msk[m]) s += __expf(vals[m] - mx);
        float lse = (mx > -1e29f) ? mx + __logf(s) : 0.f;
        ent[(b*NE_ + e)*H_ + h] = (f16)lse;
    }
}

// ---- ent_att: mean over valid mentions -> f16 [B][NE][NH][L]
__device__ void ent_att_body(int bid, const float* __restrict__ attn,
                             const int* __restrict__ mpos,
                             const int* __restrict__ mmask,
                             f16* __restrict__ eatt) {
    int nh = bid % NH_, e = (bid / NH_) % NE_, b = bid / (NH_*NE_);
    int tid = threadIdx.x;
    int l0 = tid * 4;
    const int* mp = mpos  + (b*NE_ + e)*M_;
    const int* mk = mmask + (b*NE_ + e)*M_;
    const float* abase = attn + (long long)(b*NH_ + nh) * L_ * L_;
    f32x4 acc = {0,0,0,0}; int cnt = 0;
#pragma unroll
    for (int m = 0; m < M_; m++) {
        if (mk[m]) {                       // wave-uniform branch
            cnt++;
            const float* row = abase + (long long)(mp[m] + 1) * L_;
            acc += *(const f32x4*)(row + l0);
        }
    }
    float inv = 1.f / (float)(cnt > 0 ? cnt : 1);
    f16x4 o = {(f16)(acc[0]*inv), (f16)(acc[1]*inv), (f16)(acc[2]*inv), (f16)(acc[3]*inv)};
    *(f16x4*)(eatt + ((long long)(b*NE_ + e)*NH_ + nh)*L_ + l0) = o;
}

// ---- ht: (1/NH) sum_h ea_i*ea_j, relu, L-normalize -> f16 HT [B][HTP][L]
__device__ void ht_body(int bid, char* smem, const f16* __restrict__ eatt,
                        f16* __restrict__ HT) {
    int jg = bid % 6, i = (bid / 6) % NE_, b = bid / 252;
    int tid = threadIdx.x;
    f16* ei_s = (f16*)smem;                       // 24576 B
    float (*red)[4] = (float(*)[4])(smem + NH_*L_*2);  // 7*4 floats
    const f16* ei = eatt + (long long)(b*NE_ + i)*NH_*L_;
#pragma unroll
    for (int q = 0; q < 6; q++) {
        int off = (q*256 + tid)*8;
        *(f16x8*)(ei_s + off) = *(const f16x8*)(ei + off);
    }
    __syncthreads();
    int l0 = tid*4;
    int wave = tid >> 6, lane = tid & 63;
    for (int jj = 0; jj < 7; jj++) {
        int j = jg*7 + jj;
        const f16* ej = eatt + (long long)(b*NE_ + j)*NH_*L_;
        f32x4 acc = {0,0,0,0};
#pragma unroll
        for (int h = 0; h < NH_; h++) {
            f16x4 vi = *(const f16x4*)(ei_s + h*L_ + l0);
            f16x4 vj = *(const f16x4*)(ej   + h*L_ + l0);
#pragma unroll
            for (int r = 0; r < 4; r++) acc[r] += (float)vi[r] * (float)vj[r];
        }
        float v[4]; float s = 0.f;
#pragma unroll
        for (int r = 0; r < 4; r++) {
            float t = acc[r] * (1.f/12.f);
            t = t > 0.f ? t : 0.f;
            v[r] = t; s += t;
        }
#pragma unroll
        for (int m = 1; m < 64; m <<= 1) s += __shfl_xor(s, m, 64);
        if (lane == 0) red[jj][wave] = s;
        __syncthreads();                         // single barrier: each jj has own slot
        float S = red[jj][0] + red[jj][1] + red[jj][2] + red[jj][3];
        float sc = 1.f / (S + 1e-10f);
        f16x4 o = {(f16)(v[0]*sc), (f16)(v[1]*sc), (f16)(v[2]*sc), (f16)(v[3]*sc)};
        *(f16x4*)(HT + ((long long)b*HTP_ + i*NE_ + j)*L_ + l0) = o;
    }
}

// ---- small MFMA GEMM 64x64: het = ent @ wtop^T + bcat
#define LDSS 40
__device__ void gemm_het_body(int bx, int by, char* smem,
                              const f16* __restrict__ A, const f16* __restrict__ BT,
                              float* __restrict__ het, const float* __restrict__ bcat) {
    const int M = 168, K = 768;
    f16* As = (f16*)smem;                 // 64*40*2 = 5120 B
    f16* Bs = (f16*)(smem + 64*LDSS*2);   // 5120 B
    int bm = bx*64, bn = by*64;
    int tid = threadIdx.x;
    int wave = tid >> 6, lane = tid & 63;
    int wm = (wave >> 1)*32, wn = (wave & 1)*32;
    int lo4 = lane & 15, kq = (lane >> 4)*8;
    int srow = tid >> 2, scol = (tid & 3)*8;
    bool aval = (bm + srow) < M;
    const f16* aptr = A + (long long)(bm + srow)*K + scol;
    const f16* bptr = BT + (long long)(bn + srow)*K + scol;
    f32x4 acc[2][2] = {};
    for (int k0 = 0; k0 < K; k0 += 32) {
        uint4 zero = {0,0,0,0};
        uint4 av = aval ? *(const uint4*)(aptr + k0) : zero;
        uint4 bv = *(const uint4*)(bptr + k0);
        __syncthreads();
        *(uint4*)(As + srow*LDSS + scol) = av;
        *(uint4*)(Bs + srow*LDSS + scol) = bv;
        __syncthreads();
        f16x8 a0 = *(const f16x8*)(As + (wm +      lo4)*LDSS + kq);
        f16x8 a1 = *(const f16x8*)(As + (wm + 16 + lo4)*LDSS + kq);
        f16x8 b0 = *(const f16x8*)(Bs + (wn +      lo4)*LDSS + kq);
        f16x8 b1 = *(const f16x8*)(Bs + (wn + 16 + lo4)*LDSS + kq);
        acc[0][0] = __builtin_amdgcn_mfma_f32_16x16x32_f16(a0, b0, acc[0][0], 0,0,0);
        acc[0][1] = __builtin_amdgcn_mfma_f32_16x16x32_f16(a0, b1, acc[0][1], 0,0,0);
        acc[1][0] = __builtin_amdgcn_mfma_f32_16x16x32_f16(a1, b0, acc[1][0], 0,0,0);
        acc[1][1] = __builtin_amdgcn_mfma_f32_16x16x32_f16(a1, b1, acc[1][1], 0,0,0);
    }
    int rloc = (lane >> 4)*4;      // C/D: col=lane&15, row=(lane>>4)*4+reg
#pragma unroll
    for (int sm = 0; sm < 2; sm++)
#pragma unroll
    for (int sn = 0; sn < 2; sn++) {
        f32x4 a = acc[sm][sn];
        int c  = bn + wn + sn*16 + lo4;
        int rb = bm + wm + sm*16 + rloc;
#pragma unroll
        for (int r = 0; r < 4; r++)
            if (rb + r < M) het[(rb + r)*E2_ + c] = a[r] + bcat[c];
    }
}

// ---- MFMA f16 GEMM 128x128, BK=32, global_load_lds staging.
// MODE 1: store C transposed f16 -> outp16[bz][c][l] via LDS transpose (coalesced
//         64B-contiguous stores; old path was an 8B x 2KB-stride scatter = 8x write amp)
// MODE 2: tanh + split f32 out (coalesced: c consecutive within quarter-wave)
#define LDST 72   // Ts stride (f16): 144B rows -> 16B-aligned reads, <=2-way banks
template<int MODE>
__device__ void gemm2_body(int bx, int by, int bz, char* smem,
                           const f16* __restrict__ A, const f16* __restrict__ BT, int K,
                           long long strideA, long long strideBT,
                           const float* __restrict__ het, float* __restrict__ outp,
                           f16* __restrict__ outp16) {
    f16* As = (f16*)smem;            // 8 KB, unpadded (global_load_lds)
    f16* Bs = (f16*)(smem + 8192);   // 8 KB
    int bm = bx*128, bn = by*128;
    const f16* Ab = A + strideA*bz;
    const f16* Bb = BT + strideBT*bz;
    int tid = threadIdx.x, wave = tid >> 6, lane = tid & 63;
    int wm = (wave >> 1)*64, wn = (wave & 1)*64;
    int lo4 = lane & 15, kq = (lane >> 4)*8;
    int lrow = lane >> 2, lcol = (lane & 3)*8;
    const f16* ag = Ab + (long long)(bm + wave*32 + lrow)*K + lcol;
    const f16* bg = Bb + (long long)(bn + wave*32 + lrow)*K + lcol;
    f16* asl = As + wave*1024;
    f16* bsl = Bs + wave*1024;
    f32x4 acc[4][4] = {};
    for (int k0 = 0; k0 < K; k0 += 32) {
        async16(ag + k0,          asl);
        async16(ag + k0 + 16*K,   asl + 512);
        async16(bg + k0,          bsl);
        async16(bg + k0 + 16*K,   bsl + 512);
        __syncthreads();
        f16x8 af[4], bf[4];
#pragma unroll
        for (int s = 0; s < 4; s++) {
            af[s] = *(const f16x8*)(As + (wm + s*16 + lo4)*32 + kq);
            bf[s] = *(const f16x8*)(Bs + (wn + s*16 + lo4)*32 + kq);
        }
#pragma unroll
        for (int sm = 0; sm < 4; sm++)
#pragma unroll
        for (int sn = 0; sn < 4; sn++)
            acc[sm][sn] = __builtin_amdgcn_mfma_f32_16x16x32_f16(af[sm], bf[sn], acc[sm][sn], 0,0,0);
        __syncthreads();
    }
    int rloc = (lane >> 4)*4;
    if constexpr (MODE == 1) {
        // LDS-transposed coalesced store: two 64-row (l) passes.
        f16* Ts = (f16*)smem;               // [128][LDST] f16 = 18432 B (reuses As/Bs)
        int h_of_wave = wave >> 1;          // wm == h*64
#pragma unroll
        for (int h = 0; h < 2; h++) {
            if (h_of_wave == h) {
#pragma unroll
                for (int sm = 0; sm < 4; sm++)
#pragma unroll
                for (int sn = 0; sn < 4; sn++) {
                    f32x4 a = acc[sm][sn];
                    int cl = wn + sn*16 + lo4;          // 0..127
                    int ll = sm*16 + rloc;              // 0..60
#pragma unroll
                    for (int r = 0; r < 4; r++)
                        Ts[cl*LDST + ll + r] = (f16)a[r];
                }
            }
            __syncthreads();
            {
                int cl = tid >> 1;                      // 0..127
                int lb = (tid & 1)*32;                  // 0 or 32
                f16* dst = outp16 + (long long)bz*E2_*L_
                         + (long long)(bn + cl)*L_ + bm + h*64 + lb;
                const f16* srcl = Ts + cl*LDST + lb;
#pragma unroll
                for (int q = 0; q < 4; q++)
                    *(f16x8*)(dst + q*8) = *(const f16x8*)(srcl + q*8);
            }
            __syncthreads();
        }
    } else {
#pragma unroll
        for (int sm = 0; sm < 4; sm++)
#pragma unroll
        for (int sn = 0; sn < 4; sn++) {
            f32x4 a = acc[sm][sn];
            int c  = bn + wn + sn*16 + lo4;
            int rb = bm + wm + sm*16 + rloc;
#pragma unroll
            for (int r = 0; r < 4; r++) {
                int row = rb + r;
                if (row < NE_*NE_) {
                    int i = row / NE_;
                    int j = row - i*NE_;
                    int sel = (c < H_) ? i : j;
                    float bias = het[(bz*NE_ + sel)*E2_ + c];
                    float v = fast_tanh(a[r] + bias);
                    long long o = (c < H_)
                        ? ((long long)((bz*NE_ + i)*NE_ + j))*H_ + c
                        : OUT_HALF + ((long long)((bz*NE_ + i)*NE_ + j))*H_ + (c - H_);
                    outp[o] = v;
                }
            }
        }
    }
}

// ===================== fused launches =====================
// L1: prep (2304) | seq16 (3072) | ent_emb (168) | ent_att (2016)  = 7560 blocks
__global__ __launch_bounds__(256) void k_L1(
        const float* __restrict__ seq, const float* __restrict__ attn,
        const float* __restrict__ Wh, const float* __restrict__ bh,
        const float* __restrict__ Wt, const float* __restrict__ bt,
        const int* __restrict__ mpos, const int* __restrict__ mmask,
        f16* __restrict__ wtop, f16* __restrict__ wbot, float* __restrict__ bcat,
        f16* __restrict__ seq16, f16* __restrict__ ent, f16* __restrict__ eatt) {
    __shared__ __align__(16) char smem[4224];
    int bid = blockIdx.x;
    if (bid < 2304)       prep_body(bid, smem, Wh, Wt, bh, bt, wtop, wbot, bcat);
    else if (bid < 5376)  seq16_body(bid - 2304, seq, seq16);
    else if (bid < 5544)  ent_emb_body(bid - 5376, seq, mpos, mmask, ent);
    else                  ent_att_body(bid - 5544, attn, mpos, mmask, eatt);
}

// L2: gemm2<1> (384) | ht (1008) | gemm_het (72) = 1464 blocks
__global__ __launch_bounds__(256) void k_L2(
        const f16* __restrict__ seq16, const f16* __restrict__ wbot,
        const f16* __restrict__ ent, const f16* __restrict__ wtop,
        const float* __restrict__ bcat, const f16* __restrict__ eatt,
        f16* __restrict__ seqWT, float* __restrict__ het, f16* __restrict__ HT) {
    __shared__ __align__(16) char smem[24704];
    int bid = blockIdx.x;
    if (bid < 384) {
        int bx = bid & 7, by = (bid >> 3) % 12, bz = bid / 96;
        gemm2_body<1>(bx, by, bz, smem, seq16, wbot, 768,
                      (long long)L_*H_, 0, nullptr, nullptr, seqWT);
    } else if (bid < 1392) {
        ht_body(bid - 384, smem, eatt, HT);
    } else {
        int r = bid - 1392;
        gemm_het_body(r % 3, r / 3, smem, ent, wtop, het, bcat);
    }
}

// L3: 128x128 gemm2<2>, flat grid 672 = 8 XCDs x 84, bijective XCD swizzle so each
// XCD's 84 consecutive lids cover one half-bz: 12-block runs share an A-panel (bx),
// all 12 B-panels cycle -> per-XCD unique ~4.9 MB (L2-resident).
__global__ __launch_bounds__(256) void k_L3(
        const f16* __restrict__ HT, const f16* __restrict__ seqWT,
        const float* __restrict__ het, float* __restrict__ outp) {
    __shared__ __align__(16) char smem[16384];
    int orig = blockIdx.x;
    int lid  = (orig & 7) * 84 + (orig >> 3);
    int bz   = lid / 168;
    int rem  = lid - bz*168;
    int bx   = rem / 12;
    int by   = rem - bx*12;
    gemm2_body<2>(bx, by, bz, smem, HT, seqWT, 1024,
                  (long long)HTP_*L_, (long long)E2_*L_, het, outp, nullptr);
}

extern "C" void kernel_launch(void* const* d_in, const int* in_sizes, int n_in,
                              void* d_out, int out_size, void* d_ws, size_t ws_size,
                              hipStream_t stream) {
    const float* seq  = (const float*)d_in[0];
    const float* attn = (const float*)d_in[1];
    const float* Wh   = (const float*)d_in[2];
    const float* bh   = (const float*)d_in[3];
    const float* Wt   = (const float*)d_in[4];
    const float* bt   = (const float*)d_in[5];
    const int* mpos   = (const int*)d_in[6];
    const int* mmask  = (const int*)d_in[7];
    float* out = (float*)d_out;
    char* ws = (char*)d_ws;
    f16*   ent   = (f16*)  (ws + 0);         //  168*768          f16
    f16*   wtop  = (f16*)  (ws + 258048);    // 1536*768          f16 [c][h]
    f16*   wbot  = (f16*)  (ws + 2617344);   // 1536*768          f16 [c][h]
    float* bcat  = (float*)(ws + 4976640);   // 1536              f32
    float* het   = (float*)(ws + 4982784);   //  168*1536         f32
    f16*   eatt  = (f16*)  (ws + 6014976);   // 4*42*12*1024      f16
    f16*   seq16 = (f16*)  (ws + 10143744);  // 4*1024*768        f16
    f16*   HT    = (f16*)  (ws + 16435200);  // 4*1792*1024       f16
    f16*   seqWT = (f16*)  (ws + 31115264);  // 4*1536*1024       f16 (transposed)
    // total 43,698,176 B

    k_L1<<<7560, 256, 0, stream>>>(seq, attn, Wh, bh, Wt, bt, mpos, mmask,
                                   wtop, wbot, bcat, seq16, ent, eatt);
    k_L2<<<1464, 256, 0, stream>>>(seq16, wbot, ent, wtop, bcat, eatt,
                                   seqWT, het, HT);
    k_L3<<<672, 256, 0, stream>>>(HT, seqWT, het, out);
}

// Round 6
// 349.747 us; speedup vs baseline: 1.0644x; 1.0096x over previous
//
#include <hip/hip_runtime.h>
#include <math.h>

typedef _Float16 f16;
typedef __attribute__((ext_vector_type(4))) _Float16 f16x4;
typedef __attribute__((ext_vector_type(8))) _Float16 f16x8;
typedef __attribute__((ext_vector_type(4))) float f32x4;

#define B_    4
#define L_    1024
#define H_    768
#define NH_   12
#define NE_   42
#define M_    8
#define E2_   1536              // 2*H
#define HTP_  1792              // HT rows padded to 14*128
#define OUT_HALF 5419008LL      // B*NE*NE*H

// async global->LDS, 16B per lane. LDS dest is wave-uniform base + lane*16B.
typedef __attribute__((address_space(1))) const unsigned char ga_t;
typedef __attribute__((address_space(3))) unsigned char la_t;
__device__ __forceinline__ void async16(const void* g, void* l) {
    __builtin_amdgcn_global_load_lds((ga_t*)g, (la_t*)l, 16, 0, 0);
}

// fast tanh: 1 - 2/(e^{2x}+1) via v_exp_f32. Correct limits at +-inf.
__device__ __forceinline__ float fast_tanh(float x) {
    float e = __expf(2.f * x);
    return 1.f - 2.f / (e + 1.f);
}

// ===================== device bodies =====================

// ---- prep: 32x32 LDS tile transpose W[h][c] -> w*[c][h] (f16) + bias concat
__device__ void prep_body(int bid, char* smem,
                          const float* __restrict__ Wh, const float* __restrict__ Wt,
                          const float* __restrict__ bh, const float* __restrict__ bt,
                          f16* __restrict__ wtop, f16* __restrict__ wbot,
                          float* __restrict__ bcat) {
    float (*tile)[33] = (float(*)[33])smem;           // 32*33*4 = 4224 B
    int tx = bid % 24, ty = (bid / 24) % 24, m = bid / 576;
    const float* src = (m & 1) ? Wt : Wh;
    int roff = (m & 2) ? H_ : 0;
    f16* dst = (m & 2) ? wbot : wtop;
    int coff = (m & 1) ? H_ : 0;
    int x = threadIdx.x & 31, y8 = threadIdx.x >> 5;
#pragma unroll
    for (int r = 0; r < 4; r++) {
        int h = ty*32 + y8 + r*8, c = tx*32 + x;
        tile[y8 + r*8][x] = src[(long long)(roff + h)*H_ + c];
    }
    __syncthreads();
#pragma unroll
    for (int r = 0; r < 4; r++) {
        int c2 = tx*32 + y8 + r*8, h2 = ty*32 + x;
        dst[(long long)(coff + c2)*H_ + h2] = (f16)tile[x][y8 + r*8];
    }
    if (bid == 0) {
        for (int idx = threadIdx.x; idx < E2_; idx += 256)
            bcat[idx] = (idx < H_) ? bh[idx] : bt[idx - H_];
    }
}

// ---- seq f32 -> f16
__device__ void seq16_body(int bid, const float* __restrict__ seq,
                           f16* __restrict__ seq16) {
    int idx = (bid*256 + threadIdx.x) * 4;
    f32x4 v = *(const f32x4*)(seq + idx);
    f16x4 o = {(f16)v[0], (f16)v[1], (f16)v[2], (f16)v[3]};
    *(f16x4*)(seq16 + idx) = o;
}

// ---- ent_emb: masked logsumexp over mentions -> f16 [168][768]
__device__ void ent_emb_body(int bid, const float* __restrict__ seq,
                             const int* __restrict__ mpos,
                             const int* __restrict__ mmask,
                             f16* __restrict__ ent) {
    int e = bid % NE_, b = bid / NE_;
    int tid = threadIdx.x;
    const int* mp = mpos  + (b*NE_ + e)*M_;
    const int* mk = mmask + (b*NE_ + e)*M_;
    int pos[M_], msk[M_];
#pragma unroll
    for (int m = 0; m < M_; m++) { msk[m] = mk[m]; pos[m] = mp[m] + 1; }
#pragma unroll
    for (int q = 0; q < 3; q++) {
        int h = tid + q*256;
        float mx = -1e30f, vals[M_];
#pragma unroll
        for (int m = 0; m < M_; m++) {
            vals[m] = 0.f;
            if (msk[m]) {
                float v = seq[((long long)b*L_ + pos[m])*H_ + h];
                vals[m] = v; mx = fmaxf(mx, v);
            }
        }
        float s = 0.f;
#pragma unroll
        for (int m = 0; m < M_; m++) if (msk[m]) s += __expf(vals[m] - mx);
        float lse = (mx > -1e29f) ? mx + __logf(s) : 0.f;
        ent[(b*NE_ + e)*H_ + h] = (f16)lse;
    }
}

// ---- ent_att: mean over valid mentions -> f16 [B][NE][NH][L]
__device__ void ent_att_body(int bid, const float* __restrict__ attn,
                             const int* __restrict__ mpos,
                             const int* __restrict__ mmask,
                             f16* __restrict__ eatt) {
    int nh = bid % NH_, e = (bid / NH_) % NE_, b = bid / (NH_*NE_);
    int tid = threadIdx.x;
    int l0 = tid * 4;
    const int* mp = mpos  + (b*NE_ + e)*M_;
    const int* mk = mmask + (b*NE_ + e)*M_;
    const float* abase = attn + (long long)(b*NH_ + nh) * L_ * L_;
    f32x4 acc = {0,0,0,0}; int cnt = 0;
#pragma unroll
    for (int m = 0; m < M_; m++) {
        if (mk[m]) {                       // wave-uniform branch
            cnt++;
            const float* row = abase + (long long)(mp[m] + 1) * L_;
            acc += *(const f32x4*)(row + l0);
        }
    }
    float inv = 1.f / (float)(cnt > 0 ? cnt : 1);
    f16x4 o = {(f16)(acc[0]*inv), (f16)(acc[1]*inv), (f16)(acc[2]*inv), (f16)(acc[3]*inv)};
    *(f16x4*)(eatt + ((long long)(b*NE_ + e)*NH_ + nh)*L_ + l0) = o;
}

// ---- ht: (1/NH) sum_h ea_i*ea_j, relu, L-normalize -> f16 HT [B][HTP][L]
__device__ void ht_body(int bid, char* smem, const f16* __restrict__ eatt,
                        f16* __restrict__ HT) {
    int jg = bid % 6, i = (bid / 6) % NE_, b = bid / 252;
    int tid = threadIdx.x;
    f16* ei_s = (f16*)smem;                       // 24576 B
    float (*red)[4] = (float(*)[4])(smem + NH_*L_*2);  // 7*4 floats
    const f16* ei = eatt + (long long)(b*NE_ + i)*NH_*L_;
#pragma unroll
    for (int q = 0; q < 6; q++) {
        int off = (q*256 + tid)*8;
        *(f16x8*)(ei_s + off) = *(const f16x8*)(ei + off);
    }
    __syncthreads();
    int l0 = tid*4;
    int wave = tid >> 6, lane = tid & 63;
    for (int jj = 0; jj < 7; jj++) {
        int j = jg*7 + jj;
        const f16* ej = eatt + (long long)(b*NE_ + j)*NH_*L_;
        f32x4 acc = {0,0,0,0};
#pragma unroll
        for (int h = 0; h < NH_; h++) {
            f16x4 vi = *(const f16x4*)(ei_s + h*L_ + l0);
            f16x4 vj = *(const f16x4*)(ej   + h*L_ + l0);
#pragma unroll
            for (int r = 0; r < 4; r++) acc[r] += (float)vi[r] * (float)vj[r];
        }
        float v[4]; float s = 0.f;
#pragma unroll
        for (int r = 0; r < 4; r++) {
            float t = acc[r] * (1.f/12.f);
            t = t > 0.f ? t : 0.f;
            v[r] = t; s += t;
        }
#pragma unroll
        for (int m = 1; m < 64; m <<= 1) s += __shfl_xor(s, m, 64);
        if (lane == 0) red[jj][wave] = s;
        __syncthreads();                         // single barrier: each jj has own slot
        float S = red[jj][0] + red[jj][1] + red[jj][2] + red[jj][3];
        float sc = 1.f / (S + 1e-10f);
        f16x4 o = {(f16)(v[0]*sc), (f16)(v[1]*sc), (f16)(v[2]*sc), (f16)(v[3]*sc)};
        *(f16x4*)(HT + ((long long)b*HTP_ + i*NE_ + j)*L_ + l0) = o;
    }
}

// ---- small MFMA GEMM 64x64: het = ent @ wtop^T + bcat
#define LDSS 40
__device__ void gemm_het_body(int bx, int by, char* smem,
                              const f16* __restrict__ A, const f16* __restrict__ BT,
                              float* __restrict__ het, const float* __restrict__ bcat) {
    const int M = 168, K = 768;
    f16* As = (f16*)smem;                 // 64*40*2 = 5120 B
    f16* Bs = (f16*)(smem + 64*LDSS*2);   // 5120 B
    int bm = bx*64, bn = by*64;
    int tid = threadIdx.x;
    int wave = tid >> 6, lane = tid & 63;
    int wm = (wave >> 1)*32, wn = (wave & 1)*32;
    int lo4 = lane & 15, kq = (lane >> 4)*8;
    int srow = tid >> 2, scol = (tid & 3)*8;
    bool aval = (bm + srow) < M;
    const f16* aptr = A + (long long)(bm + srow)*K + scol;
    const f16* bptr = BT + (long long)(bn + srow)*K + scol;
    f32x4 acc[2][2] = {};
    for (int k0 = 0; k0 < K; k0 += 32) {
        uint4 zero = {0,0,0,0};
        uint4 av = aval ? *(const uint4*)(aptr + k0) : zero;
        uint4 bv = *(const uint4*)(bptr + k0);
        __syncthreads();
        *(uint4*)(As + srow*LDSS + scol) = av;
        *(uint4*)(Bs + srow*LDSS + scol) = bv;
        __syncthreads();
        f16x8 a0 = *(const f16x8*)(As + (wm +      lo4)*LDSS + kq);
        f16x8 a1 = *(const f16x8*)(As + (wm + 16 + lo4)*LDSS + kq);
        f16x8 b0 = *(const f16x8*)(Bs + (wn +      lo4)*LDSS + kq);
        f16x8 b1 = *(const f16x8*)(Bs + (wn + 16 + lo4)*LDSS + kq);
        acc[0][0] = __builtin_amdgcn_mfma_f32_16x16x32_f16(a0, b0, acc[0][0], 0,0,0);
        acc[0][1] = __builtin_amdgcn_mfma_f32_16x16x32_f16(a0, b1, acc[0][1], 0,0,0);
        acc[1][0] = __builtin_amdgcn_mfma_f32_16x16x32_f16(a1, b0, acc[1][0], 0,0,0);
        acc[1][1] = __builtin_amdgcn_mfma_f32_16x16x32_f16(a1, b1, acc[1][1], 0,0,0);
    }
    int rloc = (lane >> 4)*4;      // C/D: col=lane&15, row=(lane>>4)*4+reg
#pragma unroll
    for (int sm = 0; sm < 2; sm++)
#pragma unroll
    for (int sn = 0; sn < 2; sn++) {
        f32x4 a = acc[sm][sn];
        int c  = bn + wn + sn*16 + lo4;
        int rb = bm + wm + sm*16 + rloc;
#pragma unroll
        for (int r = 0; r < 4; r++)
            if (rb + r < M) het[(rb + r)*E2_ + c] = a[r] + bcat[c];
    }
}

// ---- MFMA f16 GEMM 128x128, BK=64 single-buffer, swizzled global_load_lds staging.
// LDS per operand: [128 rows][128 B] (64 f16/row), byte col ^= ((row&7)<<4)
// (swizzle machinery identical to the r3-verified 256x256 kernel: linear LDS dest,
//  inverse-swizzled global source, swizzled ds_read; SQ_LDS_BANK_CONFLICT was 0).
// r6: BK 32->64 halves the per-iter stage+vmcnt(0)+barrier structural overhead
// (m233: ~72% of the 2-phase critical path) while keeping 32KB LDS (occupancy ~3-4/CU).
// MODE 1: store C transposed f16 -> outp16[bz][c][l] via LDS transpose
// MODE 2: tanh + split f32 out
#define LDST 72   // Ts stride (f16): 144B rows -> 16B-aligned reads, <=2-way banks
template<int MODE>
__device__ void gemm2_body(int bx, int by, int bz, char* smem,
                           const f16* __restrict__ A, const f16* __restrict__ BT, int K,
                           long long strideA, long long strideBT,
                           const float* __restrict__ het, float* __restrict__ outp,
                           f16* __restrict__ outp16) {
    char* As = smem;                 // 16 KB swizzled [128][128B]
    char* Bs = smem + 16384;         // 16 KB
    int bm = bx*128, bn = by*128;
    const f16* Ab = A + strideA*bz;
    const f16* Bb = BT + strideBT*bz;
    int tid = threadIdx.x, wave = tid >> 6, lane = tid & 63;
    int wm = (wave >> 1)*64, wn = (wave & 1)*64;
    int lo4 = lane & 15;
    int kq2 = (lane >> 4)*16;                 // byte offset of 8-f16 quarter
    int sw  = (lo4 & 7) << 4;                 // read-side swizzle
    // staging geometry: round ld in 0..3 stages rows ld*32 + (tid>>3), 16B at
    // byte col (tid&7)*16, inverse-swizzled on the global side.
    int r0    = tid >> 3;
    int scolb = ((tid & 7) * 16) ^ (((tid >> 3) & 7) << 4);
    char* adst = As + (tid & ~63)*16;         // + ld*4096 (wave-uniform base)
    char* bdst = Bs + (tid & ~63)*16;
    const char* ag = (const char*)(Ab + (long long)(bm + r0)*K) + scolb;
    const char* bg = (const char*)(Bb + (long long)(bn + r0)*K) + scolb;
    long long rstep32 = (long long)32 * K * 2;   // 32 rows in bytes
    f32x4 acc[4][4] = {};
    for (int k0 = 0; k0 < K; k0 += 64) {
        long long kb = (long long)k0 * 2;
#pragma unroll
        for (int ld = 0; ld < 4; ld++)
            async16(ag + kb + ld*rstep32, adst + ld*4096);
#pragma unroll
        for (int ld = 0; ld < 4; ld++)
            async16(bg + kb + ld*rstep32, bdst + ld*4096);
        __syncthreads();
        f16x8 af[4][2], bf[4][2];
#pragma unroll
        for (int s = 0; s < 4; s++) {
            char* pa = As + (wm + s*16 + lo4)*128;
            char* pb = Bs + (wn + s*16 + lo4)*128;
#pragma unroll
            for (int kk = 0; kk < 2; kk++) {
                af[s][kk] = *(const f16x8*)(pa + ((kk*64 + kq2) ^ sw));
                bf[s][kk] = *(const f16x8*)(pb + ((kk*64 + kq2) ^ sw));
            }
        }
#pragma unroll
        for (int sm = 0; sm < 4; sm++)
#pragma unroll
        for (int sn = 0; sn < 4; sn++) {
            acc[sm][sn] = __builtin_amdgcn_mfma_f32_16x16x32_f16(af[sm][0], bf[sn][0], acc[sm][sn], 0,0,0);
            acc[sm][sn] = __builtin_amdgcn_mfma_f32_16x16x32_f16(af[sm][1], bf[sn][1], acc[sm][sn], 0,0,0);
        }
        __syncthreads();
    }
    int rloc = (lane >> 4)*4;
    if constexpr (MODE == 1) {
        // LDS-transposed coalesced store: two 64-row (l) passes.
        f16* Ts = (f16*)smem;               // [128][LDST] f16 = 18432 B (reuses As/Bs)
        int h_of_wave = wave >> 1;          // wm == h*64
#pragma unroll
        for (int h = 0; h < 2; h++) {
            if (h_of_wave == h) {
#pragma unroll
                for (int sm = 0; sm < 4; sm++)
#pragma unroll
                for (int sn = 0; sn < 4; sn++) {
                    f32x4 a = acc[sm][sn];
                    int cl = wn + sn*16 + lo4;          // 0..127
                    int ll = sm*16 + rloc;              // 0..60
#pragma unroll
                    for (int r = 0; r < 4; r++)
                        Ts[cl*LDST + ll + r] = (f16)a[r];
                }
            }
            __syncthreads();
            {
                int cl = tid >> 1;                      // 0..127
                int lb = (tid & 1)*32;                  // 0 or 32
                f16* dst = outp16 + (long long)bz*E2_*L_
                         + (long long)(bn + cl)*L_ + bm + h*64 + lb;
                const f16* srcl = Ts + cl*LDST + lb;
#pragma unroll
                for (int q = 0; q < 4; q++)
                    *(f16x8*)(dst + q*8) = *(const f16x8*)(srcl + q*8);
            }
            __syncthreads();
        }
    } else {
#pragma unroll
        for (int sm = 0; sm < 4; sm++)
#pragma unroll
        for (int sn = 0; sn < 4; sn++) {
            f32x4 a = acc[sm][sn];
            int c  = bn + wn + sn*16 + lo4;
            int rb = bm + wm + sm*16 + rloc;
#pragma unroll
            for (int r = 0; r < 4; r++) {
                int row = rb + r;
                if (row < NE_*NE_) {
                    int i = row / NE_;
                    int j = row - i*NE_;
                    int sel = (c < H_) ? i : j;
                    float bias = het[(bz*NE_ + sel)*E2_ + c];
                    float v = fast_tanh(a[r] + bias);
                    long long o = (c < H_)
                        ? ((long long)((bz*NE_ + i)*NE_ + j))*H_ + c
                        : OUT_HALF + ((long long)((bz*NE_ + i)*NE_ + j))*H_ + (c - H_);
                    outp[o] = v;
                }
            }
        }
    }
}

// ===================== fused launches =====================
// L1: prep (2304) | seq16 (3072) | ent_emb (168) | ent_att (2016)  = 7560 blocks
__global__ __launch_bounds__(256) void k_L1(
        const float* __restrict__ seq, const float* __restrict__ attn,
        const float* __restrict__ Wh, const float* __restrict__ bh,
        const float* __restrict__ Wt, const float* __restrict__ bt,
        const int* __restrict__ mpos, const int* __restrict__ mmask,
        f16* __restrict__ wtop, f16* __restrict__ wbot, float* __restrict__ bcat,
        f16* __restrict__ seq16, f16* __restrict__ ent, f16* __restrict__ eatt) {
    __shared__ __align__(16) char smem[4224];
    int bid = blockIdx.x;
    if (bid < 2304)       prep_body(bid, smem, Wh, Wt, bh, bt, wtop, wbot, bcat);
    else if (bid < 5376)  seq16_body(bid - 2304, seq, seq16);
    else if (bid < 5544)  ent_emb_body(bid - 5376, seq, mpos, mmask, ent);
    else                  ent_att_body(bid - 5544, attn, mpos, mmask, eatt);
}

// L2: gemm2<1> (384) | ht (1008) | gemm_het (72) = 1464 blocks
__global__ __launch_bounds__(256) void k_L2(
        const f16* __restrict__ seq16, const f16* __restrict__ wbot,
        const f16* __restrict__ ent, const f16* __restrict__ wtop,
        const float* __restrict__ bcat, const f16* __restrict__ eatt,
        f16* __restrict__ seqWT, float* __restrict__ het, f16* __restrict__ HT) {
    __shared__ __align__(16) char smem[32768];
    int bid = blockIdx.x;
    if (bid < 384) {
        int bx = bid & 7, by = (bid >> 3) % 12, bz = bid / 96;
        gemm2_body<1>(bx, by, bz, smem, seq16, wbot, 768,
                      (long long)L_*H_, 0, nullptr, nullptr, seqWT);
    } else if (bid < 1392) {
        ht_body(bid - 384, smem, eatt, HT);
    } else {
        int r = bid - 1392;
        gemm_het_body(r % 3, r / 3, smem, ent, wtop, het, bcat);
    }
}

// L3: 128x128 gemm2<2>, flat grid 672 = 8 XCDs x 84, bijective XCD swizzle so each
// XCD's 84 consecutive lids cover one half-bz: 12-block runs share an A-panel (bx),
// all 12 B-panels cycle -> per-XCD unique ~4.9 MB (mostly L2-resident).
__global__ __launch_bounds__(256) void k_L3(
        const f16* __restrict__ HT, const f16* __restrict__ seqWT,
        const float* __restrict__ het, float* __restrict__ outp) {
    __shared__ __align__(16) char smem[32768];
    int orig = blockIdx.x;
    int lid  = (orig & 7) * 84 + (orig >> 3);
    int bz   = lid / 168;
    int rem  = lid - bz*168;
    int bx   = rem / 12;
    int by   = rem - bx*12;
    gemm2_body<2>(bx, by, bz, smem, HT, seqWT, 1024,
                  (long long)HTP_*L_, (long long)E2_*L_, het, outp, nullptr);
}

extern "C" void kernel_launch(void* const* d_in, const int* in_sizes, int n_in,
                              void* d_out, int out_size, void* d_ws, size_t ws_size,
                              hipStream_t stream) {
    const float* seq  = (const float*)d_in[0];
    const float* attn = (const float*)d_in[1];
    const float* Wh   = (const float*)d_in[2];
    const float* bh   = (const float*)d_in[3];
    const float* Wt   = (const float*)d_in[4];
    const float* bt   = (const float*)d_in[5];
    const int* mpos   = (const int*)d_in[6];
    const int* mmask  = (const int*)d_in[7];
    float* out = (float*)d_out;
    char* ws = (char*)d_ws;
    f16*   ent   = (f16*)  (ws + 0);         //  168*768          f16
    f16*   wtop  = (f16*)  (ws + 258048);    // 1536*768          f16 [c][h]
    f16*   wbot  = (f16*)  (ws + 2617344);   // 1536*768          f16 [c][h]
    float* bcat  = (float*)(ws + 4976640);   // 1536              f32
    float* het   = (float*)(ws + 4982784);   //  168*1536         f32
    f16*   eatt  = (f16*)  (ws + 6014976);   // 4*42*12*1024      f16
    f16*   seq16 = (f16*)  (ws + 10143744);  // 4*1024*768        f16
    f16*   HT    = (f16*)  (ws + 16435200);  // 4*1792*1024       f16
    f16*   seqWT = (f16*)  (ws + 31115264);  // 4*1536*1024       f16 (transposed)
    // total 43,698,176 B

    k_L1<<<7560, 256, 0, stream>>>(seq, attn, Wh, bh, Wt, bt, mpos, mmask,
                                   wtop, wbot, bcat, seq16, ent, eatt);
    k_L2<<<1464, 256, 0, stream>>>(seq16, wbot, ent, wtop, bcat, eatt,
                                   seqWT, het, HT);
    k_L3<<<672, 256, 0, stream>>>(HT, seqWT, het, out);
}